// Round 2
// baseline (543.731 us; speedup 1.0000x reference)
//
#include <hip/hip_runtime.h>

#define NN 16
#define PP 2048
#define KK 16
#define ACH 64        // ADD_C
#define OUT_PTS (NN*PP*3)   // 98304
#define FTS_CH 128

__device__ __forceinline__ unsigned mono32(float f) {
  unsigned u = __float_as_uint(f);
  return (u & 0x80000000u) ? ~u : (u | 0x80000000u);
}

// ---------------- prep: copies + feature transpose ----------------
__global__ __launch_bounds__(256) void prep_kernel(const float* __restrict__ pts,
                                                   const float* __restrict__ fp,
                                                   float* __restrict__ out,
                                                   float* __restrict__ ftT) {
  const int i0 = blockIdx.x * 256 + threadIdx.x;
  const int stride = gridDim.x * 256;
  for (int e = i0; e < OUT_PTS; e += stride) out[e] = pts[e];
  for (int e = i0; e < NN * ACH * PP; e += stride) {
    int n = e >> 17;            // /(64*2048)
    int rem = e & 131071;
    out[OUT_PTS + n * (FTS_CH * PP) + rem] = fp[e];
  }
  for (int e = i0; e < NN * PP * ACH; e += stride) {
    int c = e & 63;
    int np_ = e >> 6;           // n*2048+p
    ftT[e] = fp[((np_ >> 11) * 64 + c) * 2048 + (np_ & 2047)];
  }
}

// ---------------- kNN: wave per query ----------------
__global__ __launch_bounds__(256) void knn_kernel(const float* __restrict__ pts,
                                                  int* __restrict__ idx_out) {
  __shared__ __align__(16) float4 sp[PP];  // x,y,z,r  (32 KB)
  const int nb = blockIdx.x >> 6;
  const int q0 = (blockIdx.x & 63) << 5;   // 32 queries / block
  const float* bp = pts + nb * (PP * 3);
  for (int i = threadIdx.x; i < PP; i += 256) {
    float x = bp[i * 3 + 0], y = bp[i * 3 + 1], z = bp[i * 3 + 2];
    float r = __fadd_rn(__fadd_rn(__fmul_rn(x, x), __fmul_rn(y, y)), __fmul_rn(z, z));
    sp[i] = make_float4(x, y, z, r);
  }
  __syncthreads();
  const int w = threadIdx.x >> 6;
  const int l = threadIdx.x & 63;
  for (int qi = 0; qi < 8; ++qi) {
    const int q = q0 + w * 8 + qi;
    const float4 qp = sp[q];
    float d[32];
#pragma unroll
    for (int j = 0; j < 32; ++j) {
      float4 m = sp[j * 64 + l];
      // replicate reference exactly: (r_p - 2*dot) + r_q, no fma contraction
      float dot = __fadd_rn(__fadd_rn(__fmul_rn(qp.x, m.x), __fmul_rn(qp.y, m.y)),
                            __fmul_rn(qp.z, m.z));
      d[j] = __fadd_rn(__fsub_rn(qp.w, __fadd_rn(dot, dot)), m.w);
    }
    const int out_base = (nb * PP + q) * KK;
    for (int r = 0; r < KK; ++r) {
      float lm = d[0];
      int li = 0;
#pragma unroll
      for (int j = 1; j < 32; ++j) {
        bool pr = d[j] < lm;
        lm = pr ? d[j] : lm;
        li = pr ? j : li;
      }
      unsigned hi = mono32(lm);
      unsigned lo = (unsigned)((li << 6) | l);  // global candidate index
#pragma unroll
      for (int off = 32; off; off >>= 1) {
        unsigned oh = __shfl_xor(hi, off);
        unsigned ol = __shfl_xor(lo, off);
        bool t = (oh < hi) || ((oh == hi) && (ol < lo));
        hi = t ? oh : hi;
        lo = t ? ol : lo;
      }
      if (l == 0) idx_out[out_base + r] = (int)lo;
      const int slot = ((int)(lo & 63u) == l) ? (int)(lo >> 6) : -1;
#pragma unroll
      for (int j = 0; j < 32; ++j)
        if (j == slot) d[j] = 3.0e38f;
    }
  }
}

// ---------------- MLP + windowed maxpool: wave per point ----------------
__global__ __launch_bounds__(256) void mlp_kernel(
    const float* __restrict__ pts, const float* __restrict__ ftT, const int* __restrict__ idx,
    const float* __restrict__ fc1_w, const float* __restrict__ fc1_b,
    const float* __restrict__ fc2_w, const float* __restrict__ fc2_b,
    const float* __restrict__ bn1_g, const float* __restrict__ bn1_b,
    const float* __restrict__ bn2_g, const float* __restrict__ bn2_b,
    float* __restrict__ xout, int pbase) {
  __shared__ __align__(16) float rel_s[4][16][4];
  __shared__ int nbi_s[4][16];
  __shared__ __align__(16) float h1_s[4][16][32];
  const float inv = 1.0f / sqrtf(1.0f + 1e-5f);
  const int w = threadIdx.x >> 6, l = threadIdx.x & 63;
  const int c32 = l & 31;
  const float w1x = fc1_w[c32 * 3 + 0], w1y = fc1_w[c32 * 3 + 1], w1z = fc1_w[c32 * 3 + 2];
  const float b1 = fc1_b[c32];
  const float s1 = bn1_g[c32] * inv, t1 = bn1_b[c32];
  const float s2 = bn2_g[l] * inv, t2 = bn2_b[l], b2 = fc2_b[l];
  float w2r[32];
#pragma unroll
  for (int j4 = 0; j4 < 8; ++j4) {
    float4 v = *(const float4*)(fc2_w + l * 32 + j4 * 4);
    w2r[j4 * 4 + 0] = v.x; w2r[j4 * 4 + 1] = v.y;
    w2r[j4 * 4 + 2] = v.z; w2r[j4 * 4 + 3] = v.w;
  }
  for (int t = 0; t < 4; ++t) {
    const int plocal = blockIdx.x * 16 + w * 4 + t;
    const int Pg = pbase + plocal;
    const int n = Pg >> 11, p = Pg & 2047;
    if (l < 16) {
      const int nbI = idx[Pg * KK + l];
      nbi_s[w][l] = nbI;
      const float* cp = pts + (n * PP + p) * 3;
      const float* np2 = pts + (n * PP + nbI) * 3;
      rel_s[w][l][0] = np2[0] - cp[0];
      rel_s[w][l][1] = np2[1] - cp[1];
      rel_s[w][l][2] = np2[2] - cp[2];
    }
    __syncthreads();
    const int kk = l >> 5;
#pragma unroll
    for (int tt = 0; tt < 8; ++tt) {
      const int k = tt * 2 + kk;
      float rx = rel_s[w][k][0], ry = rel_s[w][k][1], rz = rel_s[w][k][2];
      float v = fmaf(rx, w1x, b1);
      v = fmaf(ry, w1y, v);
      v = fmaf(rz, w1z, v);
      v = fmaxf(fmaf(v, s1, t1), 0.0f);
      h1_s[w][k][c32] = v;
    }
    __syncthreads();
    float pm[4] = {-3.0e38f, -3.0e38f, -3.0e38f, -3.0e38f};
    float pf[4] = {-3.0e38f, -3.0e38f, -3.0e38f, -3.0e38f};
#pragma unroll
    for (int k = 0; k < KK; ++k) {
      float acc = b2;
#pragma unroll
      for (int j4 = 0; j4 < 8; ++j4) {
        float4 h = *(const float4*)&h1_s[w][k][j4 * 4];
        acc = fmaf(h.x, w2r[j4 * 4 + 0], acc);
        acc = fmaf(h.y, w2r[j4 * 4 + 1], acc);
        acc = fmaf(h.z, w2r[j4 * 4 + 2], acc);
        acc = fmaf(h.w, w2r[j4 * 4 + 3], acc);
      }
      acc = fmaxf(fmaf(acc, s2, t2), 0.0f);
      const int win = k >> 2;
      pm[win] = fmaxf(pm[win], acc);
      const float fv = ftT[(size_t)(n * PP + nbi_s[w][k]) * ACH + l];
      pf[win] = fmaxf(pf[win], fv);
    }
    *(float4*)(xout + (size_t)plocal * 512 + l * 4) = make_float4(pm[0], pm[1], pm[2], pm[3]);
    *(float4*)(xout + (size_t)plocal * 512 + 256 + l * 4) = make_float4(pf[0], pf[1], pf[2], pf[3]);
    __syncthreads();
  }
}

// shared inner-product tile: acc[4][4] += A(4pts x 4k) * B(4k x 4outs)
#define GEMM_TILE_BODY(AT, BT)                                              \
  for (int cc = 0; cc < 32; ++cc) {                                         \
    float4 af[4], bf[4];                                                    \
    _Pragma("unroll") for (int i = 0; i < 4; ++i)                           \
        af[i] = *(const float4*)&(AT)[(ty * 4 + i) * 128 + cc * 4];         \
    _Pragma("unroll") for (int dd = 0; dd < 4; ++dd)                        \
        bf[dd] = *(const float4*)&(BT)[(cc * 4 + dd) * 64 + tx * 4];        \
    _Pragma("unroll") for (int i = 0; i < 4; ++i) {                         \
      acc[i][0] = fmaf(af[i].x, bf[0].x, acc[i][0]);                        \
      acc[i][1] = fmaf(af[i].x, bf[0].y, acc[i][1]);                        \
      acc[i][2] = fmaf(af[i].x, bf[0].z, acc[i][2]);                        \
      acc[i][3] = fmaf(af[i].x, bf[0].w, acc[i][3]);                        \
      acc[i][0] = fmaf(af[i].y, bf[1].x, acc[i][0]);                        \
      acc[i][1] = fmaf(af[i].y, bf[1].y, acc[i][1]);                        \
      acc[i][2] = fmaf(af[i].y, bf[1].z, acc[i][2]);                        \
      acc[i][3] = fmaf(af[i].y, bf[1].w, acc[i][3]);                        \
      acc[i][0] = fmaf(af[i].z, bf[2].x, acc[i][0]);                        \
      acc[i][1] = fmaf(af[i].z, bf[2].y, acc[i][1]);                        \
      acc[i][2] = fmaf(af[i].z, bf[2].z, acc[i][2]);                        \
      acc[i][3] = fmaf(af[i].z, bf[2].w, acc[i][3]);                        \
      acc[i][0] = fmaf(af[i].w, bf[3].x, acc[i][0]);                        \
      acc[i][1] = fmaf(af[i].w, bf[3].y, acc[i][1]);                        \
      acc[i][2] = fmaf(af[i].w, bf[3].z, acc[i][2]);                        \
      acc[i][3] = fmaf(af[i].w, bf[3].w, acc[i][3]);                        \
    }                                                                       \
  }

// ---------------- grouped conv1 + bias + BN3 + ReLU ----------------
__global__ __launch_bounds__(256) void conv1_kernel(
    const float* __restrict__ xin, const float* __restrict__ w1,
    const float* __restrict__ cb1, const float* __restrict__ bn3_g,
    const float* __restrict__ bn3_b, float* __restrict__ yout) {
  __shared__ __align__(16) float aT[64 * 128];
  __shared__ __align__(16) float bT[128 * 64];
  const int pl0 = blockIdx.x * 64;
  const int g = blockIdx.y;
#pragma unroll
  for (int t = 0; t < 8; ++t) {
    const int f4 = threadIdx.x + t * 256;
    const int r = f4 >> 5, c4 = f4 & 31;
    *(float4*)&aT[r * 128 + c4 * 4] =
        *(const float4*)(xin + (size_t)(pl0 + r) * 512 + g * 128 + c4 * 4);
  }
#pragma unroll
  for (int t = 0; t < 8; ++t) {
    const int i4 = threadIdx.x + t * 256;
    const int o = i4 >> 5, cq = i4 & 31;
    float4 v = *(const float4*)(w1 + (size_t)(g * 64 + o) * 128 + cq * 4);
    bT[(cq * 4 + 0) * 64 + o] = v.x;
    bT[(cq * 4 + 1) * 64 + o] = v.y;
    bT[(cq * 4 + 2) * 64 + o] = v.z;
    bT[(cq * 4 + 3) * 64 + o] = v.w;
  }
  __syncthreads();
  const int tx = threadIdx.x & 15, ty = threadIdx.x >> 4;
  float acc[4][4] = {{0.f, 0.f, 0.f, 0.f}, {0.f, 0.f, 0.f, 0.f},
                     {0.f, 0.f, 0.f, 0.f}, {0.f, 0.f, 0.f, 0.f}};
  GEMM_TILE_BODY(aT, bT)
  const float inv = 1.0f / sqrtf(1.0f + 1e-5f);
  float s[4], tb[4], cb[4];
#pragma unroll
  for (int j = 0; j < 4; ++j) {
    const int o = g * 64 + tx * 4 + j;
    s[j] = bn3_g[o] * inv;
    tb[j] = bn3_b[o];
    cb[j] = cb1[o];
  }
#pragma unroll
  for (int i = 0; i < 4; ++i) {
    float4 v;
    v.x = fmaxf(fmaf(acc[i][0] + cb[0], s[0], tb[0]), 0.0f);
    v.y = fmaxf(fmaf(acc[i][1] + cb[1], s[1], tb[1]), 0.0f);
    v.z = fmaxf(fmaf(acc[i][2] + cb[2], s[2], tb[2]), 0.0f);
    v.w = fmaxf(fmaf(acc[i][3] + cb[3], s[3], tb[3]), 0.0f);
    *(float4*)(yout + (size_t)(pl0 + ty * 4 + i) * 256 + g * 64 + tx * 4) = v;
  }
}

// ---------------- conv2 (1x1) + bias, write to out ----------------
__global__ __launch_bounds__(256) void conv2_kernel(
    const float* __restrict__ yin, const float* __restrict__ w2,
    const float* __restrict__ cb2, float* __restrict__ out, int pbase) {
  __shared__ __align__(16) float aT[64 * 128];
  __shared__ __align__(16) float bT[128 * 64];
  const int pl0 = blockIdx.x * 64;
  const int tx = threadIdx.x & 15, ty = threadIdx.x >> 4;
  float acc[4][4] = {{0.f, 0.f, 0.f, 0.f}, {0.f, 0.f, 0.f, 0.f},
                     {0.f, 0.f, 0.f, 0.f}, {0.f, 0.f, 0.f, 0.f}};
  for (int kc = 0; kc < 2; ++kc) {
#pragma unroll
    for (int t = 0; t < 8; ++t) {
      const int f4 = threadIdx.x + t * 256;
      const int r = f4 >> 5, c4 = f4 & 31;
      *(float4*)&aT[r * 128 + c4 * 4] =
          *(const float4*)(yin + (size_t)(pl0 + r) * 256 + kc * 128 + c4 * 4);
    }
#pragma unroll
    for (int t = 0; t < 8; ++t) {
      const int i4 = threadIdx.x + t * 256;
      const int o = i4 >> 5, cq = i4 & 31;
      float4 v = *(const float4*)(w2 + (size_t)o * 256 + kc * 128 + cq * 4);
      bT[(cq * 4 + 0) * 64 + o] = v.x;
      bT[(cq * 4 + 1) * 64 + o] = v.y;
      bT[(cq * 4 + 2) * 64 + o] = v.z;
      bT[(cq * 4 + 3) * 64 + o] = v.w;
    }
    __syncthreads();
    GEMM_TILE_BODY(aT, bT)
    __syncthreads();
  }
  float cb[4];
#pragma unroll
  for (int j = 0; j < 4; ++j) cb[j] = cb2[tx * 4 + j];
#pragma unroll
  for (int i = 0; i < 4; ++i)
#pragma unroll
    for (int j = 0; j < 4; ++j)
      aT[(tx * 4 + j) * 65 + (ty * 4 + i)] = acc[i][j] + cb[j];
  __syncthreads();
  const int Pg0 = pbase + pl0;
  const int n = Pg0 >> 11, pl = Pg0 & 2047;
#pragma unroll
  for (int t = 0; t < 16; ++t) {
    const int e = threadIdx.x + t * 256;
    const int o = e >> 6, pt = e & 63;
    out[OUT_PTS + (size_t)(n * FTS_CH + ACH + o) * PP + pl + pt] = aT[o * 65 + pt];
  }
}

extern "C" void kernel_launch(void* const* d_in, const int* in_sizes, int n_in,
                              void* d_out, int out_size, void* d_ws, size_t ws_size,
                              hipStream_t stream) {
  const float* pts   = (const float*)d_in[0];
  const float* fp    = (const float*)d_in[1];
  const float* fc1_w = (const float*)d_in[2];
  const float* fc1_b = (const float*)d_in[3];
  const float* fc2_w = (const float*)d_in[4];
  const float* fc2_b = (const float*)d_in[5];
  const float* bn1_g = (const float*)d_in[6];
  const float* bn1_b = (const float*)d_in[7];
  const float* bn2_g = (const float*)d_in[8];
  const float* bn2_b = (const float*)d_in[9];
  const float* bn3_g = (const float*)d_in[10];
  const float* bn3_b = (const float*)d_in[11];
  const float* w1    = (const float*)d_in[12];
  const float* cb1   = (const float*)d_in[13];
  const float* w2    = (const float*)d_in[14];
  const float* cb2   = (const float*)d_in[15];
  float* out = (float*)d_out;

  // workspace layout: [idx: 524288 int][ftT: 2097152 f][x: chunk*512 f][y: chunk*256 f]
  int* ws_idx   = (int*)d_ws;
  float* ws_f   = (float*)d_ws;
  float* ws_ftT = ws_f + 524288;
  float* ws_x   = ws_ftT + (size_t)NN * PP * ACH;
  const size_t fixed_bytes = (524288ull + 2097152ull) * 4ull;
  int nc = 1;
  while (nc < 64) {
    size_t need = fixed_bytes + ((size_t)(NN * PP / nc)) * 768ull * 4ull;
    if (need <= ws_size) break;
    nc <<= 1;
  }
  const int cpts = NN * PP / nc;
  float* ws_y = ws_x + (size_t)cpts * 512;

  prep_kernel<<<1024, 256, 0, stream>>>(pts, fp, out, ws_ftT);
  knn_kernel<<<NN * (PP / 32), 256, 0, stream>>>(pts, ws_idx);
  for (int ci = 0; ci < nc; ++ci) {
    const int pbase = ci * cpts;
    mlp_kernel<<<cpts / 16, 256, 0, stream>>>(pts, ws_ftT, ws_idx, fc1_w, fc1_b, fc2_w, fc2_b,
                                              bn1_g, bn1_b, bn2_g, bn2_b, ws_x, pbase);
    conv1_kernel<<<dim3(cpts / 64, 4), 256, 0, stream>>>(ws_x, w1, cb1, bn3_g, bn3_b, ws_y);
    conv2_kernel<<<cpts / 64, 256, 0, stream>>>(ws_y, w2, cb2, out, pbase);
  }
}

// Round 3
// 377.642 us; speedup vs baseline: 1.4398x; 1.4398x over previous
//
#include <hip/hip_runtime.h>

#define NN 16
#define PP 2048
#define KK 16
#define ACH 64        // ADD_C
#define OUT_PTS (NN*PP*3)   // 98304
#define FTS_CH 128
#define SCAP 128      // survivor cap per query (fallback if exceeded)

__device__ __forceinline__ unsigned mono32(float f) {
  unsigned u = __float_as_uint(f);
  return (u & 0x80000000u) ? ~u : (u | 0x80000000u);
}

#define F32_INF __int_as_float(0x7f800000)

// ---- DPP wave64 min reductions (VALU-speed, no LDS latency) ----
template <int CTRL, int RMASK>
__device__ __forceinline__ float dppmin_f(float v) {
  int mv = __builtin_amdgcn_update_dpp(0x7f800000, __float_as_int(v), CTRL, RMASK, 0xf, false);
  return fminf(v, __int_as_float(mv));
}
template <int CTRL, int RMASK>
__device__ __forceinline__ unsigned dppmin_u(unsigned v) {
  unsigned mv = (unsigned)__builtin_amdgcn_update_dpp((int)0xFFFFFFFFu, (int)v, CTRL, RMASK, 0xf, false);
  return v < mv ? v : mv;
}
// full-wave min, broadcast to all lanes via readlane(63)
__device__ __forceinline__ float wave_min_f(float v) {
  v = dppmin_f<0x111, 0xf>(v);  // row_shr:1
  v = dppmin_f<0x112, 0xf>(v);  // row_shr:2
  v = dppmin_f<0x114, 0xf>(v);  // row_shr:4
  v = dppmin_f<0x118, 0xf>(v);  // row_shr:8
  v = dppmin_f<0x142, 0xa>(v);  // row_bcast:15 -> rows 1,3
  v = dppmin_f<0x143, 0xc>(v);  // row_bcast:31 -> rows 2,3
  return __int_as_float(__builtin_amdgcn_readlane(__float_as_int(v), 63));
}
__device__ __forceinline__ unsigned wave_min_u(unsigned v) {
  v = dppmin_u<0x111, 0xf>(v);
  v = dppmin_u<0x112, 0xf>(v);
  v = dppmin_u<0x114, 0xf>(v);
  v = dppmin_u<0x118, 0xf>(v);
  v = dppmin_u<0x142, 0xa>(v);
  v = dppmin_u<0x143, 0xc>(v);
  return (unsigned)__builtin_amdgcn_readlane((int)v, 63);
}

// ---------------- prep: copies + feature transpose ----------------
__global__ __launch_bounds__(256) void prep_kernel(const float* __restrict__ pts,
                                                   const float* __restrict__ fp,
                                                   float* __restrict__ out,
                                                   float* __restrict__ ftT) {
  const int i0 = blockIdx.x * 256 + threadIdx.x;
  const int stride = gridDim.x * 256;
  for (int e = i0; e < OUT_PTS; e += stride) out[e] = pts[e];
  for (int e = i0; e < NN * ACH * PP; e += stride) {
    int n = e >> 17;            // /(64*2048)
    int rem = e & 131071;
    out[OUT_PTS + n * (FTS_CH * PP) + rem] = fp[e];
  }
  for (int e = i0; e < NN * PP * ACH; e += stride) {
    int c = e & 63;
    int np_ = e >> 6;           // n*2048+p
    ftT[e] = fp[((np_ >> 11) * 64 + c) * 2048 + (np_ & 2047)];
  }
}

// ---------------- kNN: wave per query, tau-prefilter + DPP argmin ----------------
__global__ __launch_bounds__(256) void knn_kernel(const float* __restrict__ pts,
                                                  int* __restrict__ idx_out) {
  __shared__ __align__(16) float4 sp[PP];         // 32 KB
  __shared__ float sd[4][SCAP];                   // survivor dists (2 KB)
  __shared__ unsigned si[4][SCAP];                // survivor ids   (2 KB)
  const int nb = blockIdx.x >> 6;
  const int q0 = (blockIdx.x & 63) << 5;   // 32 queries / block
  const float* bp = pts + nb * (PP * 3);
  for (int i = threadIdx.x; i < PP; i += 256) {
    float x = bp[i * 3 + 0], y = bp[i * 3 + 1], z = bp[i * 3 + 2];
    float r = __fadd_rn(__fadd_rn(__fmul_rn(x, x), __fmul_rn(y, y)), __fmul_rn(z, z));
    sp[i] = make_float4(x, y, z, r);
  }
  __syncthreads();
  const int w = threadIdx.x >> 6;
  const int l = threadIdx.x & 63;
  for (int qi = 0; qi < 8; ++qi) {
    const int q = q0 + w * 8 + qi;
    const float4 qp = sp[q];
    float d[32];
#pragma unroll
    for (int j = 0; j < 32; ++j) {
      float4 m = sp[j * 64 + l];
      // replicate reference exactly: (r_p - 2*dot) + r_q, no fma contraction
      float dot = __fadd_rn(__fadd_rn(__fmul_rn(qp.x, m.x), __fmul_rn(qp.y, m.y)),
                            __fmul_rn(qp.z, m.z));
      d[j] = __fadd_rn(__fsub_rn(qp.w, __fadd_rn(dot, dot)), m.w);
    }
    const int out_base = (nb * PP + q) * KK;

    // ---- lane-local min (balanced tree; fuses to v_min3) ----
    float m16[16];
#pragma unroll
    for (int j = 0; j < 16; ++j) m16[j] = fminf(d[j], d[j + 16]);
#pragma unroll
    for (int j = 0; j < 8; ++j) m16[j] = fminf(m16[j], m16[j + 8]);
#pragma unroll
    for (int j = 0; j < 4; ++j) m16[j] = fminf(m16[j], m16[j + 4]);
    float lmv = fminf(fminf(m16[0], m16[1]), fminf(m16[2], m16[3]));

    // ---- tau = 16th smallest of the 64 lane minima ----
    // (the 16 evicted lane-minima are 16 distinct candidates <= tau => d16 <= tau)
    float tau = 0.0f;
#pragma unroll 1
    for (int r = 0; r < 16; ++r) {
      float dmin = wave_min_f(lmv);
      if (r == 15) { tau = dmin; break; }
      unsigned long long mk = __ballot(lmv == dmin);
      int wlane = __ffsll(mk) - 1;
      if (l == wlane) lmv = F32_INF;
    }

    // ---- ballot-compact survivors (d <= tau) into LDS ----
    int base = 0;
#pragma unroll
    for (int j = 0; j < 32; ++j) {
      bool keep = (d[j] <= tau);
      unsigned long long mk = __ballot(keep);
      if (mk) {
        int pre = __builtin_amdgcn_mbcnt_hi((unsigned)(mk >> 32),
                  __builtin_amdgcn_mbcnt_lo((unsigned)mk, 0));
        if (keep) {
          int off = base + pre;
          if (off < SCAP) { sd[w][off] = d[j]; si[w][off] = (unsigned)(j * 64 + l); }
        }
        base += __popcll(mk);
      }
    }
    const int M = base;  // >= 16 guaranteed

    if (M <= SCAP) {
      // ---- fast path: 16 rounds over <=2 survivors/lane, exact (dist,id) order ----
      float c0 = F32_INF, c1 = F32_INF;
      unsigned i0 = 0xFFFFFFFFu, i1 = 0xFFFFFFFFu;
      if (l < M)      { c0 = sd[w][l];      i0 = si[w][l]; }
      if (64 + l < M) { c1 = sd[w][64 + l]; i1 = si[w][64 + l]; }
#pragma unroll 1
      for (int r = 0; r < KK; ++r) {
        bool s1 = (c1 < c0) || ((c1 == c0) && (i1 < i0));
        float lm = s1 ? c1 : c0;
        unsigned li = s1 ? i1 : i0;
        float dmin = wave_min_f(lm);
        unsigned wid = (lm == dmin) ? li : 0xFFFFFFFFu;
        unsigned widm = wave_min_u(wid);
        if (l == 0) idx_out[out_base + r] = (int)widm;
        if (i0 == widm) { c0 = F32_INF; i0 = 0xFFFFFFFFu; }
        if (i1 == widm) { c1 = F32_INF; i1 = 0xFFFFFFFFu; }
      }
    } else {
      // ---- dense fallback (rare/adversarial): original proven path ----
#pragma unroll 1
      for (int r = 0; r < KK; ++r) {
        float lm = d[0];
        int li = 0;
#pragma unroll
        for (int j = 1; j < 32; ++j) {
          bool pr = d[j] < lm;
          lm = pr ? d[j] : lm;
          li = pr ? j : li;
        }
        unsigned hi = mono32(lm);
        unsigned lo = (unsigned)((li << 6) | l);
#pragma unroll
        for (int off = 32; off; off >>= 1) {
          unsigned oh = __shfl_xor(hi, off);
          unsigned ol = __shfl_xor(lo, off);
          bool t = (oh < hi) || ((oh == hi) && (ol < lo));
          hi = t ? oh : hi;
          lo = t ? ol : lo;
        }
        if (l == 0) idx_out[out_base + r] = (int)lo;
        const int slot = ((int)(lo & 63u) == l) ? (int)(lo >> 6) : -1;
#pragma unroll
        for (int j = 0; j < 32; ++j)
          if (j == slot) d[j] = 3.0e38f;
      }
    }
  }
}

// ---------------- MLP + windowed maxpool: wave per point ----------------
__global__ __launch_bounds__(256) void mlp_kernel(
    const float* __restrict__ pts, const float* __restrict__ ftT, const int* __restrict__ idx,
    const float* __restrict__ fc1_w, const float* __restrict__ fc1_b,
    const float* __restrict__ fc2_w, const float* __restrict__ fc2_b,
    const float* __restrict__ bn1_g, const float* __restrict__ bn1_b,
    const float* __restrict__ bn2_g, const float* __restrict__ bn2_b,
    float* __restrict__ xout, int pbase) {
  __shared__ __align__(16) float rel_s[4][16][4];
  __shared__ int nbi_s[4][16];
  __shared__ __align__(16) float h1_s[4][16][32];
  const float inv = 1.0f / sqrtf(1.0f + 1e-5f);
  const int w = threadIdx.x >> 6, l = threadIdx.x & 63;
  const int c32 = l & 31;
  const float w1x = fc1_w[c32 * 3 + 0], w1y = fc1_w[c32 * 3 + 1], w1z = fc1_w[c32 * 3 + 2];
  const float b1 = fc1_b[c32];
  const float s1 = bn1_g[c32] * inv, t1 = bn1_b[c32];
  const float s2 = bn2_g[l] * inv, t2 = bn2_b[l], b2 = fc2_b[l];
  float w2r[32];
#pragma unroll
  for (int j4 = 0; j4 < 8; ++j4) {
    float4 v = *(const float4*)(fc2_w + l * 32 + j4 * 4);
    w2r[j4 * 4 + 0] = v.x; w2r[j4 * 4 + 1] = v.y;
    w2r[j4 * 4 + 2] = v.z; w2r[j4 * 4 + 3] = v.w;
  }
  for (int t = 0; t < 4; ++t) {
    const int plocal = blockIdx.x * 16 + w * 4 + t;
    const int Pg = pbase + plocal;
    const int n = Pg >> 11, p = Pg & 2047;
    if (l < 16) {
      const int nbI = idx[Pg * KK + l];
      nbi_s[w][l] = nbI;
      const float* cp = pts + (n * PP + p) * 3;
      const float* np2 = pts + (n * PP + nbI) * 3;
      rel_s[w][l][0] = np2[0] - cp[0];
      rel_s[w][l][1] = np2[1] - cp[1];
      rel_s[w][l][2] = np2[2] - cp[2];
    }
    __syncthreads();
    const int kk = l >> 5;
#pragma unroll
    for (int tt = 0; tt < 8; ++tt) {
      const int k = tt * 2 + kk;
      float rx = rel_s[w][k][0], ry = rel_s[w][k][1], rz = rel_s[w][k][2];
      float v = fmaf(rx, w1x, b1);
      v = fmaf(ry, w1y, v);
      v = fmaf(rz, w1z, v);
      v = fmaxf(fmaf(v, s1, t1), 0.0f);
      h1_s[w][k][c32] = v;
    }
    __syncthreads();
    float pm[4] = {-3.0e38f, -3.0e38f, -3.0e38f, -3.0e38f};
    float pf[4] = {-3.0e38f, -3.0e38f, -3.0e38f, -3.0e38f};
#pragma unroll
    for (int k = 0; k < KK; ++k) {
      float acc = b2;
#pragma unroll
      for (int j4 = 0; j4 < 8; ++j4) {
        float4 h = *(const float4*)&h1_s[w][k][j4 * 4];
        acc = fmaf(h.x, w2r[j4 * 4 + 0], acc);
        acc = fmaf(h.y, w2r[j4 * 4 + 1], acc);
        acc = fmaf(h.z, w2r[j4 * 4 + 2], acc);
        acc = fmaf(h.w, w2r[j4 * 4 + 3], acc);
      }
      acc = fmaxf(fmaf(acc, s2, t2), 0.0f);
      const int win = k >> 2;
      pm[win] = fmaxf(pm[win], acc);
      const float fv = ftT[(size_t)(n * PP + nbi_s[w][k]) * ACH + l];
      pf[win] = fmaxf(pf[win], fv);
    }
    *(float4*)(xout + (size_t)plocal * 512 + l * 4) = make_float4(pm[0], pm[1], pm[2], pm[3]);
    *(float4*)(xout + (size_t)plocal * 512 + 256 + l * 4) = make_float4(pf[0], pf[1], pf[2], pf[3]);
    __syncthreads();
  }
}

// shared inner-product tile: acc[4][4] += A(4pts x 4k) * B(4k x 4outs)
#define GEMM_TILE_BODY(AT, BT)                                              \
  for (int cc = 0; cc < 32; ++cc) {                                         \
    float4 af[4], bf[4];                                                    \
    _Pragma("unroll") for (int i = 0; i < 4; ++i)                           \
        af[i] = *(const float4*)&(AT)[(ty * 4 + i) * 128 + cc * 4];         \
    _Pragma("unroll") for (int dd = 0; dd < 4; ++dd)                        \
        bf[dd] = *(const float4*)&(BT)[(cc * 4 + dd) * 64 + tx * 4];        \
    _Pragma("unroll") for (int i = 0; i < 4; ++i) {                         \
      acc[i][0] = fmaf(af[i].x, bf[0].x, acc[i][0]);                        \
      acc[i][1] = fmaf(af[i].x, bf[0].y, acc[i][1]);                        \
      acc[i][2] = fmaf(af[i].x, bf[0].z, acc[i][2]);                        \
      acc[i][3] = fmaf(af[i].x, bf[0].w, acc[i][3]);                        \
      acc[i][0] = fmaf(af[i].y, bf[1].x, acc[i][0]);                        \
      acc[i][1] = fmaf(af[i].y, bf[1].y, acc[i][1]);                        \
      acc[i][2] = fmaf(af[i].y, bf[1].z, acc[i][2]);                        \
      acc[i][3] = fmaf(af[i].y, bf[1].w, acc[i][3]);                        \
      acc[i][0] = fmaf(af[i].z, bf[2].x, acc[i][0]);                        \
      acc[i][1] = fmaf(af[i].z, bf[2].y, acc[i][1]);                        \
      acc[i][2] = fmaf(af[i].z, bf[2].z, acc[i][2]);                        \
      acc[i][3] = fmaf(af[i].z, bf[2].w, acc[i][3]);                        \
      acc[i][0] = fmaf(af[i].w, bf[3].x, acc[i][0]);                        \
      acc[i][1] = fmaf(af[i].w, bf[3].y, acc[i][1]);                        \
      acc[i][2] = fmaf(af[i].w, bf[3].z, acc[i][2]);                        \
      acc[i][3] = fmaf(af[i].w, bf[3].w, acc[i][3]);                        \
    }                                                                       \
  }

// ---------------- grouped conv1 + bias + BN3 + ReLU ----------------
__global__ __launch_bounds__(256) void conv1_kernel(
    const float* __restrict__ xin, const float* __restrict__ w1,
    const float* __restrict__ cb1, const float* __restrict__ bn3_g,
    const float* __restrict__ bn3_b, float* __restrict__ yout) {
  __shared__ __align__(16) float aT[64 * 128];
  __shared__ __align__(16) float bT[128 * 64];
  const int pl0 = blockIdx.x * 64;
  const int g = blockIdx.y;
#pragma unroll
  for (int t = 0; t < 8; ++t) {
    const int f4 = threadIdx.x + t * 256;
    const int r = f4 >> 5, c4 = f4 & 31;
    *(float4*)&aT[r * 128 + c4 * 4] =
        *(const float4*)(xin + (size_t)(pl0 + r) * 512 + g * 128 + c4 * 4);
  }
#pragma unroll
  for (int t = 0; t < 8; ++t) {
    const int i4 = threadIdx.x + t * 256;
    const int o = i4 >> 5, cq = i4 & 31;
    float4 v = *(const float4*)(w1 + (size_t)(g * 64 + o) * 128 + cq * 4);
    bT[(cq * 4 + 0) * 64 + o] = v.x;
    bT[(cq * 4 + 1) * 64 + o] = v.y;
    bT[(cq * 4 + 2) * 64 + o] = v.z;
    bT[(cq * 4 + 3) * 64 + o] = v.w;
  }
  __syncthreads();
  const int tx = threadIdx.x & 15, ty = threadIdx.x >> 4;
  float acc[4][4] = {{0.f, 0.f, 0.f, 0.f}, {0.f, 0.f, 0.f, 0.f},
                     {0.f, 0.f, 0.f, 0.f}, {0.f, 0.f, 0.f, 0.f}};
  GEMM_TILE_BODY(aT, bT)
  const float inv = 1.0f / sqrtf(1.0f + 1e-5f);
  float s[4], tb[4], cb[4];
#pragma unroll
  for (int j = 0; j < 4; ++j) {
    const int o = g * 64 + tx * 4 + j;
    s[j] = bn3_g[o] * inv;
    tb[j] = bn3_b[o];
    cb[j] = cb1[o];
  }
#pragma unroll
  for (int i = 0; i < 4; ++i) {
    float4 v;
    v.x = fmaxf(fmaf(acc[i][0] + cb[0], s[0], tb[0]), 0.0f);
    v.y = fmaxf(fmaf(acc[i][1] + cb[1], s[1], tb[1]), 0.0f);
    v.z = fmaxf(fmaf(acc[i][2] + cb[2], s[2], tb[2]), 0.0f);
    v.w = fmaxf(fmaf(acc[i][3] + cb[3], s[3], tb[3]), 0.0f);
    *(float4*)(yout + (size_t)(pl0 + ty * 4 + i) * 256 + g * 64 + tx * 4) = v;
  }
}

// ---------------- conv2 (1x1) + bias, write to out ----------------
__global__ __launch_bounds__(256) void conv2_kernel(
    const float* __restrict__ yin, const float* __restrict__ w2,
    const float* __restrict__ cb2, float* __restrict__ out, int pbase) {
  __shared__ __align__(16) float aT[64 * 128];
  __shared__ __align__(16) float bT[128 * 64];
  const int pl0 = blockIdx.x * 64;
  const int tx = threadIdx.x & 15, ty = threadIdx.x >> 4;
  float acc[4][4] = {{0.f, 0.f, 0.f, 0.f}, {0.f, 0.f, 0.f, 0.f},
                     {0.f, 0.f, 0.f, 0.f}, {0.f, 0.f, 0.f, 0.f}};
  for (int kc = 0; kc < 2; ++kc) {
#pragma unroll
    for (int t = 0; t < 8; ++t) {
      const int f4 = threadIdx.x + t * 256;
      const int r = f4 >> 5, c4 = f4 & 31;
      *(float4*)&aT[r * 128 + c4 * 4] =
          *(const float4*)(yin + (size_t)(pl0 + r) * 256 + kc * 128 + c4 * 4);
    }
#pragma unroll
    for (int t = 0; t < 8; ++t) {
      const int i4 = threadIdx.x + t * 256;
      const int o = i4 >> 5, cq = i4 & 31;
      float4 v = *(const float4*)(w2 + (size_t)o * 256 + kc * 128 + cq * 4);
      bT[(cq * 4 + 0) * 64 + o] = v.x;
      bT[(cq * 4 + 1) * 64 + o] = v.y;
      bT[(cq * 4 + 2) * 64 + o] = v.z;
      bT[(cq * 4 + 3) * 64 + o] = v.w;
    }
    __syncthreads();
    GEMM_TILE_BODY(aT, bT)
    __syncthreads();
  }
  float cb[4];
#pragma unroll
  for (int j = 0; j < 4; ++j) cb[j] = cb2[tx * 4 + j];
#pragma unroll
  for (int i = 0; i < 4; ++i)
#pragma unroll
    for (int j = 0; j < 4; ++j)
      aT[(tx * 4 + j) * 65 + (ty * 4 + i)] = acc[i][j] + cb[j];
  __syncthreads();
  const int Pg0 = pbase + pl0;
  const int n = Pg0 >> 11, pl = Pg0 & 2047;
#pragma unroll
  for (int t = 0; t < 16; ++t) {
    const int e = threadIdx.x + t * 256;
    const int o = e >> 6, pt = e & 63;
    out[OUT_PTS + (size_t)(n * FTS_CH + ACH + o) * PP + pl + pt] = aT[o * 65 + pt];
  }
}

extern "C" void kernel_launch(void* const* d_in, const int* in_sizes, int n_in,
                              void* d_out, int out_size, void* d_ws, size_t ws_size,
                              hipStream_t stream) {
  const float* pts   = (const float*)d_in[0];
  const float* fp    = (const float*)d_in[1];
  const float* fc1_w = (const float*)d_in[2];
  const float* fc1_b = (const float*)d_in[3];
  const float* fc2_w = (const float*)d_in[4];
  const float* fc2_b = (const float*)d_in[5];
  const float* bn1_g = (const float*)d_in[6];
  const float* bn1_b = (const float*)d_in[7];
  const float* bn2_g = (const float*)d_in[8];
  const float* bn2_b = (const float*)d_in[9];
  const float* bn3_g = (const float*)d_in[10];
  const float* bn3_b = (const float*)d_in[11];
  const float* w1    = (const float*)d_in[12];
  const float* cb1   = (const float*)d_in[13];
  const float* w2    = (const float*)d_in[14];
  const float* cb2   = (const float*)d_in[15];
  float* out = (float*)d_out;

  // workspace layout: [idx: 524288 int][ftT: 2097152 f][x: chunk*512 f][y: chunk*256 f]
  int* ws_idx   = (int*)d_ws;
  float* ws_f   = (float*)d_ws;
  float* ws_ftT = ws_f + 524288;
  float* ws_x   = ws_ftT + (size_t)NN * PP * ACH;
  const size_t fixed_bytes = (524288ull + 2097152ull) * 4ull;
  int nc = 1;
  while (nc < 64) {
    size_t need = fixed_bytes + ((size_t)(NN * PP / nc)) * 768ull * 4ull;
    if (need <= ws_size) break;
    nc <<= 1;
  }
  const int cpts = NN * PP / nc;
  float* ws_y = ws_x + (size_t)cpts * 512;

  prep_kernel<<<1024, 256, 0, stream>>>(pts, fp, out, ws_ftT);
  knn_kernel<<<NN * (PP / 32), 256, 0, stream>>>(pts, ws_idx);
  for (int ci = 0; ci < nc; ++ci) {
    const int pbase = ci * cpts;
    mlp_kernel<<<cpts / 16, 256, 0, stream>>>(pts, ws_ftT, ws_idx, fc1_w, fc1_b, fc2_w, fc2_b,
                                              bn1_g, bn1_b, bn2_g, bn2_b, ws_x, pbase);
    conv1_kernel<<<dim3(cpts / 64, 4), 256, 0, stream>>>(ws_x, w1, cb1, bn3_g, bn3_b, ws_y);
    conv2_kernel<<<cpts / 64, 256, 0, stream>>>(ws_y, w2, cb2, out, pbase);
  }
}